// Round 1
// baseline (787.157 us; speedup 1.0000x reference)
//
#include <hip/hip_runtime.h>
#include <hip/hip_bf16.h>

typedef __attribute__((ext_vector_type(8))) short short8;
typedef __attribute__((ext_vector_type(4))) float floatx4;

#define B_C 4
#define NEW_C 512
#define CACHE_C 4096
#define TOTAL_C 4608
#define H_C 32
#define HKV_C 8
#define D_C 128
#define HID_C 4096
#define QKV_N 6144

__device__ __forceinline__ unsigned short f2bf(float f) {
  union { float f; unsigned u; } v; v.f = f;
  unsigned r = v.u + 0x7FFFu + ((v.u >> 16) & 1u);
  return (unsigned short)(r >> 16);
}
__device__ __forceinline__ float bf2f(unsigned short h) {
  union { unsigned u; float f; } v; v.u = ((unsigned)h) << 16; return v.f;
}
__device__ __forceinline__ void gload_lds16(const unsigned short* g, unsigned short* lds) {
  __builtin_amdgcn_global_load_lds(
      (const __attribute__((address_space(1))) unsigned int*)g,
      (__attribute__((address_space(3))) unsigned int*)lds, 16, 0, 0);
}

// ---------------- RMSNorm: x f32 (2048x4096) -> hn bf16 ----------------
__global__ __launch_bounds__(256) void rmsnorm_k(const float* __restrict__ x,
                                                 const float* __restrict__ g,
                                                 unsigned short* __restrict__ hn) {
  const int row = blockIdx.x;
  const int t = threadIdx.x;
  const float4* xr = (const float4*)(x + (size_t)row * 4096);
  float4 v[4];
  float ss = 0.f;
#pragma unroll
  for (int i = 0; i < 4; ++i) {
    v[i] = xr[t + i * 256];
    ss += v[i].x * v[i].x + v[i].y * v[i].y + v[i].z * v[i].z + v[i].w * v[i].w;
  }
#pragma unroll
  for (int m = 1; m < 64; m <<= 1) ss += __shfl_xor(ss, m);
  __shared__ float red[4];
  if ((t & 63) == 0) red[t >> 6] = ss;
  __syncthreads();
  ss = red[0] + red[1] + red[2] + red[3];
  const float inv = rsqrtf(ss * (1.f / 4096.f) + 1e-6f);
  const float4* gw = (const float4*)g;
#pragma unroll
  for (int i = 0; i < 4; ++i) {
    float4 w4 = gw[t + i * 256];
    ushort4 o;
    o.x = f2bf(v[i].x * inv * w4.x);
    o.y = f2bf(v[i].y * inv * w4.y);
    o.z = f2bf(v[i].z * inv * w4.z);
    o.w = f2bf(v[i].w * inv * w4.w);
    *(ushort4*)&hn[(size_t)row * 4096 + (t + i * 256) * 4] = o;
  }
}

// ---- build wqkvT bf16 (6144 x 4096): wqkvT[n][k] = {wq|wk|wv}[k][n] ----
__global__ __launch_bounds__(256) void build_wqkvT_k(const float* __restrict__ wq,
                                                     const float* __restrict__ wk,
                                                     const float* __restrict__ wv,
                                                     unsigned short* __restrict__ out) {
  __shared__ float tile[32][33];
  const int n0 = blockIdx.x * 32, k0 = blockIdx.y * 32;
  const float* src; int ld, nc;
  if (n0 < 4096)      { src = wq; ld = 4096; nc = n0; }
  else if (n0 < 5120) { src = wk; ld = 1024; nc = n0 - 4096; }
  else                { src = wv; ld = 1024; nc = n0 - 5120; }
  const int t = threadIdx.x, r = t >> 3, cv = (t & 7) * 4;
  const float4 v = *(const float4*)&src[(size_t)(k0 + r) * ld + nc + cv];
  tile[r][cv + 0] = v.x; tile[r][cv + 1] = v.y; tile[r][cv + 2] = v.z; tile[r][cv + 3] = v.w;
  __syncthreads();
  ushort4 o;
  o.x = f2bf(tile[cv + 0][r]); o.y = f2bf(tile[cv + 1][r]);
  o.z = f2bf(tile[cv + 2][r]); o.w = f2bf(tile[cv + 3][r]);
  *(ushort4*)&out[(size_t)(n0 + r) * 4096 + k0 + cv] = o;
}

// ---- generic f32->bf16 32x32 transpose: dst[c][r] = src[r][c] ----
__global__ __launch_bounds__(256) void transpose_cvt_k(const float* __restrict__ src,
                                                       long sbs_hi, long sbs_lo, int sld,
                                                       unsigned short* __restrict__ dst,
                                                       long dbs, int dld) {
  __shared__ float tile[32][33];
  const int z = blockIdx.z;
  const long sb = (long)(z >> 3) * sbs_hi + (long)(z & 7) * sbs_lo;
  const long db = (long)z * dbs;
  const int r0 = blockIdx.y * 32, c0 = blockIdx.x * 32;
  const int t = threadIdx.x, r = t >> 3, cv = (t & 7) * 4;
  const float4 v = *(const float4*)&src[sb + (long)(r0 + r) * sld + c0 + cv];
  tile[r][cv + 0] = v.x; tile[r][cv + 1] = v.y; tile[r][cv + 2] = v.z; tile[r][cv + 3] = v.w;
  __syncthreads();
  ushort4 o;
  o.x = f2bf(tile[cv + 0][r]); o.y = f2bf(tile[cv + 1][r]);
  o.z = f2bf(tile[cv + 2][r]); o.w = f2bf(tile[cv + 3][r]);
  *(ushort4*)&dst[db + (long)(c0 + r) * dld + r0 + cv] = o;
}

// ---- u16 32x32 transpose (no convert): dst[c][r] = src[r][c] ----
__global__ __launch_bounds__(256) void transpose_u16_k(const unsigned short* __restrict__ src,
                                                       long sbs, int sld,
                                                       unsigned short* __restrict__ dst,
                                                       long dbs, int dld) {
  __shared__ unsigned short tile[32][36];
  const int z = blockIdx.z;
  const long sb = (long)z * sbs;
  const long db = (long)z * dbs;
  const int r0 = blockIdx.y * 32, c0 = blockIdx.x * 32;
  const int t = threadIdx.x, r = t >> 3, cv = (t & 7) * 4;
  const ushort4 v = *(const ushort4*)&src[sb + (long)(r0 + r) * sld + c0 + cv];
  tile[r][cv + 0] = v.x; tile[r][cv + 1] = v.y; tile[r][cv + 2] = v.z; tile[r][cv + 3] = v.w;
  __syncthreads();
  ushort4 o;
  o.x = tile[cv + 0][r]; o.y = tile[cv + 1][r]; o.z = tile[cv + 2][r]; o.w = tile[cv + 3][r];
  *(ushort4*)&dst[db + (long)(c0 + r) * dld + r0 + cv] = o;
}

// ---- k_cache f32 (B,TOTAL,HKV,D) s<CACHE -> K_all bf16 (B,HKV,TOTAL,D) ----
__global__ __launch_bounds__(256) void cvt_kcache_k(const float* __restrict__ kc,
                                                    unsigned short* __restrict__ Kall) {
  const long i = (long)blockIdx.x * 256 + threadIdx.x;  // over 4*8*4096*32 float4
  const long c = i & 31, s = (i >> 5) & 4095, h = (i >> 17) & 7, b = i >> 20;
  const float4 v = *(const float4*)&kc[((b * 4608 + s) * 8 + h) * 128 + c * 4];
  ushort4 o;
  o.x = f2bf(v.x); o.y = f2bf(v.y); o.z = f2bf(v.z); o.w = f2bf(v.w);
  *(ushort4*)&Kall[((b * 8 + h) * 4608L + s) * 128 + c * 4] = o;
}

// ---- RoPE: qkv bf16 row -> q_rope bf16, K_all[s=CACHE+n] bf16 ----
__global__ __launch_bounds__(256) void rope_k(const unsigned short* __restrict__ qkv,
                                              const float* __restrict__ cosb,
                                              const float* __restrict__ sinb,
                                              unsigned short* __restrict__ qr,
                                              unsigned short* __restrict__ Kall) {
  const int row = blockIdx.x;
  const int b = row >> 9, n = row & 511;
  const unsigned short* src = qkv + (size_t)row * QKV_N;
  const float* cr = cosb + (size_t)row * 128;
  const float* sr = sinb + (size_t)row * 128;
  const int t = threadIdx.x;
#pragma unroll
  for (int i = 0; i < 8; ++i) {  // Q: 32 heads * 64 pairs
    int pid = t + i * 256;
    int hd = pid >> 6, d = pid & 63;
    int idx = hd * 128 + d;
    float a = bf2f(src[idx]), bb = bf2f(src[idx + 64]);
    float c0 = cr[d], s0 = sr[d], c1 = cr[d + 64], s1 = sr[d + 64];
    qr[(size_t)row * 4096 + idx] = f2bf(a * c0 - bb * s0);
    qr[(size_t)row * 4096 + idx + 64] = f2bf(bb * c1 + a * s1);
  }
#pragma unroll
  for (int i = 0; i < 2; ++i) {  // K: 8 heads * 64 pairs
    int pid = t + i * 256;
    int hd = pid >> 6, d = pid & 63;
    float a = bf2f(src[4096 + hd * 128 + d]), bb = bf2f(src[4096 + hd * 128 + d + 64]);
    float c0 = cr[d], s0 = sr[d], c1 = cr[d + 64], s1 = sr[d + 64];
    long kb = ((long)(b * 8 + hd) * TOTAL_C + CACHE_C + n) * 128 + d;
    Kall[kb] = f2bf(a * c0 - bb * s0);
    Kall[kb + 64] = f2bf(bb * c1 + a * s1);
  }
}

// ---------------- GEMM: C(MxN) = A(MxK) * BT(NxK)^T, bf16 MFMA ----------------
template <int EPI>
__global__ __launch_bounds__(256) void gemm_bt(const unsigned short* __restrict__ A,
                                               const unsigned short* __restrict__ BT,
                                               unsigned short* __restrict__ Cbf,
                                               float* __restrict__ Cf,
                                               const float* __restrict__ resid,
                                               int M, int N, int K) {
  __shared__ unsigned short As[128 * 32];
  __shared__ unsigned short Bs[128 * 32];
  const int n0 = blockIdx.x * 128, m0 = blockIdx.y * 128;
  const int t = threadIdx.x, w = t >> 6, l = t & 63;
  const int l15 = l & 15, lhi = l >> 4;
  const int wm = (w >> 1) * 64, wn = (w & 1) * 64;
  floatx4 acc[4][4];
#pragma unroll
  for (int mt = 0; mt < 4; ++mt)
#pragma unroll
    for (int nt = 0; nt < 4; ++nt)
#pragma unroll
      for (int r = 0; r < 4; ++r) acc[mt][nt][r] = 0.f;

  const int c0 = w * 2, c1 = w * 2 + 1;
  const unsigned short* ga0 = A + (size_t)(m0 + c0 * 16 + (l >> 2)) * K + (l & 3) * 8;
  const unsigned short* ga1 = A + (size_t)(m0 + c1 * 16 + (l >> 2)) * K + (l & 3) * 8;
  const unsigned short* gb0 = BT + (size_t)(n0 + c0 * 16 + (l >> 2)) * K + (l & 3) * 8;
  const unsigned short* gb1 = BT + (size_t)(n0 + c1 * 16 + (l >> 2)) * K + (l & 3) * 8;
  unsigned short* lA0 = &As[c0 * 512];
  unsigned short* lA1 = &As[c1 * 512];
  unsigned short* lB0 = &Bs[c0 * 512];
  unsigned short* lB1 = &Bs[c1 * 512];

  for (int k0 = 0; k0 < K; k0 += 32) {
    gload_lds16(ga0 + k0, lA0);
    gload_lds16(ga1 + k0, lA1);
    gload_lds16(gb0 + k0, lB0);
    gload_lds16(gb1 + k0, lB1);
    __syncthreads();
    short8 af[4], bf[4];
#pragma unroll
    for (int i = 0; i < 4; ++i) {
      af[i] = *(const short8*)&As[(wm + i * 16 + l15) * 32 + lhi * 8];
      bf[i] = *(const short8*)&Bs[(wn + i * 16 + l15) * 32 + lhi * 8];
    }
#pragma unroll
    for (int mt = 0; mt < 4; ++mt)
#pragma unroll
      for (int nt = 0; nt < 4; ++nt)
        acc[mt][nt] = __builtin_amdgcn_mfma_f32_16x16x32_bf16(af[mt], bf[nt], acc[mt][nt], 0, 0, 0);
    __syncthreads();
  }
#pragma unroll
  for (int mt = 0; mt < 4; ++mt)
#pragma unroll
    for (int nt = 0; nt < 4; ++nt)
#pragma unroll
      for (int r = 0; r < 4; ++r) {
        const int row = m0 + wm + mt * 16 + lhi * 4 + r;
        const int col = n0 + wn + nt * 16 + l15;
        const size_t idx = (size_t)row * N + col;
        if (EPI == 0) Cbf[idx] = f2bf(acc[mt][nt][r]);
        else Cf[idx] = acc[mt][nt][r] + resid[idx];
      }
}

// ---------------- Flash attention: QT=128 rows (32n x 4g), SB=32 ----------------
__global__ __launch_bounds__(512) void attn_k(const unsigned short* __restrict__ Q,
                                              const unsigned short* __restrict__ Kall,
                                              const unsigned short* __restrict__ VT,
                                              unsigned short* __restrict__ O) {
  __shared__ unsigned short Kt[32][136];
  __shared__ unsigned short Vt[128][40];
  __shared__ unsigned short Pl[8][16][40];
  const int qt = blockIdx.x, hk = blockIdx.y, b = blockIdx.z;
  const int t = threadIdx.x, w = t >> 6, l = t & 63;
  const int l15 = l & 15, lhi = l >> 4;

  short8 qf[4];
  {
    const long qrow = (long)(b * 512 + qt * 32 + w * 4 + (l15 >> 2)) * 4096 + (hk * 4 + (l15 & 3)) * 128;
#pragma unroll
    for (int kc = 0; kc < 4; ++kc) qf[kc] = *(const short8*)&Q[qrow + kc * 32 + lhi * 8];
  }
  floatx4 oacc[8];
#pragma unroll
  for (int dt = 0; dt < 8; ++dt)
#pragma unroll
    for (int r = 0; r < 4; ++r) oacc[dt][r] = 0.f;
  float mrun[4], lsum[4];
#pragma unroll
  for (int r = 0; r < 4; ++r) { mrun[r] = -1e30f; lsum[r] = 0.f; }

  const unsigned short* Kb = Kall + (long)(b * 8 + hk) * TOTAL_C * 128;
  const unsigned short* Vb = VT + (long)(b * 8 + hk) * 128 * TOTAL_C;
  const int qpos = CACHE_C + qt * 32 + w * 4 + lhi;
  const int nblk = 129 + qt;
  const float scale = 0.08838834764831845f;  // 1/sqrt(128)

  const int ksi = t >> 4, kdp = (t & 15) * 8;
  const int vdv = t >> 2, vsp = (t & 3) * 8;

  for (int sb = 0; sb < nblk; ++sb) {
    const int s0 = sb * 32;
    *(short8*)&Kt[ksi][kdp] = *(const short8*)&Kb[(long)(s0 + ksi) * 128 + kdp];
    *(short8*)&Vt[vdv][vsp] = *(const short8*)&Vb[(long)vdv * TOTAL_C + s0 + vsp];
    __syncthreads();

    floatx4 sa0, sa1;
#pragma unroll
    for (int r = 0; r < 4; ++r) { sa0[r] = 0.f; sa1[r] = 0.f; }
#pragma unroll
    for (int kc = 0; kc < 4; ++kc) {
      short8 b0 = *(const short8*)&Kt[l15][kc * 32 + lhi * 8];
      short8 b1 = *(const short8*)&Kt[16 + l15][kc * 32 + lhi * 8];
      sa0 = __builtin_amdgcn_mfma_f32_16x16x32_bf16(qf[kc], b0, sa0, 0, 0, 0);
      sa1 = __builtin_amdgcn_mfma_f32_16x16x32_bf16(qf[kc], b1, sa1, 0, 0, 0);
    }
    const bool msk0 = (s0 + l15) > qpos;
    const bool msk1 = (s0 + 16 + l15) > qpos;
    float p0[4], p1[4], bm[4], ps[4], sco[4];
#pragma unroll
    for (int r = 0; r < 4; ++r) {
      p0[r] = msk0 ? -1e30f : sa0[r] * scale;
      p1[r] = msk1 ? -1e30f : sa1[r] * scale;
      bm[r] = fmaxf(p0[r], p1[r]);
    }
#pragma unroll
    for (int m = 1; m < 16; m <<= 1)
#pragma unroll
      for (int r = 0; r < 4; ++r) bm[r] = fmaxf(bm[r], __shfl_xor(bm[r], m));
#pragma unroll
    for (int r = 0; r < 4; ++r) {
      float mn = fmaxf(mrun[r], bm[r]);
      sco[r] = __expf(mrun[r] - mn);
      mrun[r] = mn;
      p0[r] = __expf(p0[r] - mn);
      p1[r] = __expf(p1[r] - mn);
      ps[r] = p0[r] + p1[r];
    }
#pragma unroll
    for (int m = 1; m < 16; m <<= 1)
#pragma unroll
      for (int r = 0; r < 4; ++r) ps[r] += __shfl_xor(ps[r], m);
#pragma unroll
    for (int r = 0; r < 4; ++r) lsum[r] = lsum[r] * sco[r] + ps[r];
#pragma unroll
    for (int dt = 0; dt < 8; ++dt)
#pragma unroll
      for (int r = 0; r < 4; ++r) oacc[dt][r] *= sco[r];
#pragma unroll
    for (int r = 0; r < 4; ++r) {
      Pl[w][lhi * 4 + r][l15] = f2bf(p0[r]);
      Pl[w][lhi * 4 + r][16 + l15] = f2bf(p1[r]);
    }
    asm volatile("s_waitcnt lgkmcnt(0)" ::: "memory");
    short8 pa = *(const short8*)&Pl[w][l15][lhi * 8];
#pragma unroll
    for (int dt = 0; dt < 8; ++dt) {
      short8 bv = *(const short8*)&Vt[dt * 16 + l15][lhi * 8];
      oacc[dt] = __builtin_amdgcn_mfma_f32_16x16x32_bf16(pa, bv, oacc[dt], 0, 0, 0);
    }
    __syncthreads();
  }
#pragma unroll
  for (int r = 0; r < 4; ++r) {
    const float inv = 1.f / lsum[r];
    const long ob = (long)(b * 512 + qt * 32 + w * 4 + lhi) * 4096 + (hk * 4 + r) * 128 + l15;
#pragma unroll
    for (int dt = 0; dt < 8; ++dt) O[ob + dt * 16] = f2bf(oacc[dt][r] * inv);
  }
}

extern "C" void kernel_launch(void* const* d_in, const int* in_sizes, int n_in,
                              void* d_out, int out_size, void* d_ws, size_t ws_size,
                              hipStream_t stream) {
  const float* x = (const float*)d_in[0];
  const float* cosb = (const float*)d_in[1];
  const float* sinb = (const float*)d_in[2];
  const float* lnw = (const float*)d_in[3];
  const float* wq = (const float*)d_in[4];
  const float* wk = (const float*)d_in[5];
  const float* wv = (const float*)d_in[6];
  const float* wo = (const float*)d_in[7];
  const float* kcache = (const float*)d_in[8];
  const float* vcache = (const float*)d_in[9];
  float* out = (float*)d_out;
  char* ws = (char*)d_ws;

  unsigned short* hn    = (unsigned short*)(ws + 0);          // 16.8 MB
  unsigned short* wqkvT = (unsigned short*)(ws + 16777216);   // 50.3 MB
  unsigned short* qkv   = (unsigned short*)(ws + 67108864);   // 25.2 MB
  unsigned short* qrope = (unsigned short*)(ws + 92274688);   // 16.8 MB
  unsigned short* Kall  = (unsigned short*)(ws + 109051904);  // 37.75 MB
  unsigned short* VallT = (unsigned short*)(ws + 146800640);  // 37.75 MB
  unsigned short* attno = hn;     // alias: hn dead after QKV GEMM
  unsigned short* woT   = wqkvT;  // alias: wqkvT dead after QKV GEMM

  rmsnorm_k<<<2048, 256, 0, stream>>>(x, lnw, hn);
  build_wqkvT_k<<<dim3(192, 128), 256, 0, stream>>>(wq, wk, wv, wqkvT);
  gemm_bt<0><<<dim3(48, 16), 256, 0, stream>>>(hn, wqkvT, qkv, nullptr, nullptr, 2048, 6144, 4096);
  rope_k<<<2048, 256, 0, stream>>>(qkv, cosb, sinb, qrope, Kall);
  // new V (bf16, no rope): qkv[:,5120:6144] (2048x1024) -> VallT[...][CACHE+n]
  transpose_u16_k<<<dim3(32, 16, 4), 256, 0, stream>>>(qkv + 5120, 512L * QKV_N, QKV_N,
                                                       VallT + CACHE_C, 4718592L, TOTAL_C);
  // cached K: permute+convert
  cvt_kcache_k<<<16384, 256, 0, stream>>>(kcache, Kall);
  // cached V: transpose+convert  (z = b*8+h; src base = b*4718592 + h*128)
  transpose_cvt_k<<<dim3(4, 128, 32), 256, 0, stream>>>(vcache, 4718592L, 128L, 1024,
                                                        VallT, 589824L, TOTAL_C);
  attn_k<<<dim3(16, 8, 4), 512, 0, stream>>>(qrope, Kall, VallT, attno);
  // woT bf16 (4096x4096) = wo^T
  transpose_cvt_k<<<dim3(128, 128, 1), 256, 0, stream>>>(wo, 0L, 0L, 4096, woT, 0L, 4096);
  gemm_bt<1><<<dim3(32, 16), 256, 0, stream>>>(attno, woT, nullptr, out, x, 2048, 4096, 4096);
}